// Round 10
// baseline (10252.494 us; speedup 1.0000x reference)
//
#include <hip/hip_runtime.h>

// Tanh RNN: B=64, S=2048, I=H=512, fp32 in/out.
//
// Round 10 = round 8 (verified passing, 6823 us rnn) + ONE change:
// the in-loop __syncthreads() is replaced by an LDS-only barrier
// (s_waitcnt lgkmcnt(0) + s_barrier). hipcc's __syncthreads drains
// vmcnt(0) too, which forced every step to wait for HBM store-acks of the
// out-tile (~5000 cy/step). Out-stores are never read by another wave and
// xp loads are consumed via data-dependency waits, so vmcnt drain at the
// barrier is unnecessary. xp loads for t+1 are issued BEFORE the out
// stores (vmcnt retires oldest-first -> consuming loads needs vmcnt(8),
// not a full store drain).
//
// Structure (verified round 8): 8 WGs, zero inter-WG comm; WG r owns batch
// rows r*8..+8, full j range. Weights: kk0..7 in AGPR (64 frags, "+a" pin),
// kk8..11 in VGPR (32 frags, "+v" pin), kk12..15 in LDS. h double-buffer in
// LDS as [kk][lg][row] 16B entries. 4 waves, wave w owns j in [w*128,+128).

typedef _Float16 half8 __attribute__((ext_vector_type(8)));
typedef _Float16 half4 __attribute__((ext_vector_type(4)));
typedef float f32x4 __attribute__((ext_vector_type(4)));
typedef unsigned long long u64;

#define S_SZ 2048
#define OUT1_OFF 67108864ull   // S*B*H floats

// workspace offsets (bytes)
#define XP_OFF    0ull              // 2048*64*512*2 = 134217728
#define WHH_OFF   134217728ull      // 524288
#define WIH_OFF   134742016ull      // 524288
#define BIAS_OFF  135266304ull      // 2048

#define WLDS_SZ   131072            // 16 chunks * 8192 B (kk 12..15 x lg 0..3)
#define HB_SZ     8192              // one h buffer: 16kk*4lg*8row*16B
#define SMEM_SZ   147456            // WLDS + 2*HB

__device__ __forceinline__ float fast_tanh(float x) {
    float a = exp2f(x * 2.8853900817779268f);
    return (a - 1.0f) * __builtin_amdgcn_rcpf(a + 1.0f);
}

__global__ void prep_kernel(const float* __restrict__ wih, const float* __restrict__ whh,
                            const float* __restrict__ bih, const float* __restrict__ bhh,
                            _Float16* __restrict__ wih16, _Float16* __restrict__ whh16,
                            float* __restrict__ bias)
{
    const int i = blockIdx.x * 256 + threadIdx.x;   // 1024 blocks -> 262144
    wih16[i] = (_Float16)wih[i];
    whh16[i] = (_Float16)whh[i];
    if (i < 512) bias[i] = bih[i] + bhh[i];
}

// ---------------- input projection GEMM (verified rounds 3-8) ----------------
__global__ __launch_bounds__(512, 1) void xproj_kernel(
    const float* __restrict__ inputs, const _Float16* __restrict__ wih16,
    const float* __restrict__ bias, _Float16* __restrict__ xp16)
{
    __shared__ _Float16 Alds[64 * 512];
    const int s = blockIdx.x;

    for (int idx = threadIdx.x; idx < 64 * 128; idx += 512) {
        const int row = idx >> 7, chunk = idx & 127;
        const float4 v = *reinterpret_cast<const float4*>(
            inputs + ((size_t)row * S_SZ + s) * 512 + chunk * 4);
        half4 hv;
        hv[0] = (_Float16)v.x; hv[1] = (_Float16)v.y;
        hv[2] = (_Float16)v.z; hv[3] = (_Float16)v.w;
        const int bc = (chunk * 8) ^ ((row & 7) << 4);
        *reinterpret_cast<half4*>(reinterpret_cast<char*>(Alds) + row * 1024 + bc) = hv;
    }
    __syncthreads();

    const int lane = threadIdx.x & 63, w = threadIdx.x >> 6;
    const int l15 = lane & 15, lg = lane >> 4;

    f32x4 acc[4][4];
    #pragma unroll
    for (int m = 0; m < 4; ++m)
        #pragma unroll
        for (int n = 0; n < 4; ++n)
            acc[m][n] = 0.0f;

    for (int kk = 0; kk < 16; ++kk) {
        half8 af[4], bf[4];
        #pragma unroll
        for (int m = 0; m < 4; ++m) {
            const int row = m * 16 + l15;
            const int bc = (kk * 64 + lg * 16) ^ ((row & 7) << 4);
            af[m] = *reinterpret_cast<const half8*>(
                reinterpret_cast<const char*>(Alds) + row * 1024 + bc);
        }
        #pragma unroll
        for (int n = 0; n < 4; ++n) {
            const int col = w * 64 + n * 16 + l15;
            bf[n] = *reinterpret_cast<const half8*>(wih16 + (size_t)col * 512 + kk * 32 + lg * 8);
        }
        #pragma unroll
        for (int m = 0; m < 4; ++m)
            #pragma unroll
            for (int n = 0; n < 4; ++n)
                acc[m][n] = __builtin_amdgcn_mfma_f32_16x16x32_f16(bf[n], af[m], acc[m][n], 0, 0, 0);
    }

    #pragma unroll
    for (int m = 0; m < 4; ++m) {
        const int brow = m * 16 + l15;
        #pragma unroll
        for (int n = 0; n < 4; ++n) {
            const int j0 = w * 64 + n * 16 + lg * 4;
            const float4 bv = *reinterpret_cast<const float4*>(bias + j0);
            half4 hv;
            hv[0] = (_Float16)(acc[m][n][0] + bv.x);
            hv[1] = (_Float16)(acc[m][n][1] + bv.y);
            hv[2] = (_Float16)(acc[m][n][2] + bv.z);
            hv[3] = (_Float16)(acc[m][n][3] + bv.w);
            *reinterpret_cast<half4*>(xp16 + ((size_t)s * 64 + brow) * 512 + j0) = hv;
        }
    }
}

// ---------------- recurrence: pinned-register weights, LDS-only barrier ----------------
__global__ __launch_bounds__(256, 1) void rnn_step_kernel(
    const _Float16* __restrict__ whh16, const _Float16* __restrict__ xp16,
    const float* __restrict__ state, float* __restrict__ out)
{
    extern __shared__ __align__(16) char smem[];
    char* wlds = smem;                 // 16 chunks * 8192
    char* hb   = smem + WLDS_SZ;       // 2 * 8192

    const int r = blockIdx.x;          // 0..7: batch rows r*8..+8
    const int tid = threadIdx.x;
    const int lane = tid & 63, w = tid >> 6;   // 4 waves; wave w: j in [w*128, +128)
    const int l15 = lane & 15, lg = lane >> 4;
    const int row8 = l15 & 7;
    const bool primary = (l15 < 8);

    // --- stage W-LDS (kk 12..15), linear: chunk c=(kk-12)*4+lgc, entry jj ---
    for (int idx = tid; idx < 16 * 512; idx += 256) {
        const int c = idx >> 9, jj = idx & 511;
        const int kk = 12 + (c >> 2), lgc = c & 3;
        *reinterpret_cast<half8*>(wlds + c * 8192 + jj * 16) =
            *reinterpret_cast<const half8*>(whh16 + (size_t)jj * 512 + kk * 32 + lgc * 8);
    }
    // --- stage h0 as [kk][lg][row] entries: h[row][kk*32+lg*8 .. +8] ---
    for (int idx = tid; idx < 512; idx += 256) {
        const int row = idx & 7, lgc = (idx >> 3) & 3, kk = idx >> 5;
        const float* sp = state + (size_t)(r * 8 + row) * 512 + kk * 32 + lgc * 8;
        const float4 v0 = *reinterpret_cast<const float4*>(sp);
        const float4 v1 = *reinterpret_cast<const float4*>(sp + 4);
        half8 hv;
        hv[0] = (_Float16)v0.x; hv[1] = (_Float16)v0.y;
        hv[2] = (_Float16)v0.z; hv[3] = (_Float16)v0.w;
        hv[4] = (_Float16)v1.x; hv[5] = (_Float16)v1.y;
        hv[6] = (_Float16)v1.z; hv[7] = (_Float16)v1.w;
        *reinterpret_cast<half8*>(hb + ((kk * 4 + lgc) * 8 + row) * 16) = hv;
    }

    // --- register weights: wa (kk0..7 -> AGPR) + wv (kk8..11 -> VGPR) ---
    half8 wa[64], wv[32];
    {
        const _Float16* wp = whh16 + (size_t)(w * 128 + l15) * 512 + lg * 8;
        #pragma unroll
        for (int jt = 0; jt < 8; ++jt) {
            #pragma unroll
            for (int kk = 0; kk < 8; ++kk)
                wa[jt * 8 + kk] = *reinterpret_cast<const half8*>(wp + jt * 16 * 512 + kk * 32);
            #pragma unroll
            for (int kk = 8; kk < 12; ++kk)
                wv[jt * 4 + kk - 8] = *reinterpret_cast<const half8*>(wp + jt * 16 * 512 + kk * 32);
        }
    }
    // pin: opaque def blocks remat; "a"/"v" fixes the register class.
    #pragma unroll
    for (int i = 0; i < 64; ++i) asm volatile("" : "+a"(wa[i]));
    #pragma unroll
    for (int i = 0; i < 32; ++i) asm volatile("" : "+v"(wv[i]));

    // --- xp prefetch for t=0 ---
    u64 xq[8];
    {
        const _Float16* xpb = xp16 + (size_t)(r * 8 + row8) * 512 + w * 128 + lg * 4;
        #pragma unroll
        for (int jt = 0; jt < 8; ++jt)
            xq[jt] = *reinterpret_cast<const u64*>(xpb + jt * 16);
    }

    __syncthreads();   // staging barrier (once; full drain is fine here)

    #pragma unroll 1
    for (int t = 0; t < S_SZ; ++t) {
        const char* hc = hb + (t & 1) * HB_SZ;
        char* hn = hb + ((t + 1) & 1) * HB_SZ;

        f32x4 acc[8];
        #pragma unroll
        for (int jt = 0; jt < 8; ++jt) acc[jt] = 0.0f;

        // kk 0..7: AGPR-resident weights
        #pragma unroll
        for (int kk = 0; kk < 8; ++kk) {
            const half8 bf = *reinterpret_cast<const half8*>(
                hc + ((kk * 4 + lg) * 8 + row8) * 16);
            #pragma unroll
            for (int jt = 0; jt < 8; ++jt)
                acc[jt] = __builtin_amdgcn_mfma_f32_16x16x32_f16(
                    wa[jt * 8 + kk], bf, acc[jt], 0, 0, 0);
        }
        // kk 8..11: VGPR-resident weights
        #pragma unroll
        for (int kk = 8; kk < 12; ++kk) {
            const half8 bf = *reinterpret_cast<const half8*>(
                hc + ((kk * 4 + lg) * 8 + row8) * 16);
            #pragma unroll
            for (int jt = 0; jt < 8; ++jt)
                acc[jt] = __builtin_amdgcn_mfma_f32_16x16x32_f16(
                    wv[jt * 4 + kk - 8], bf, acc[jt], 0, 0, 0);
        }
        // kk 12..15: weights from LDS
        #pragma unroll
        for (int kk = 12; kk < 16; ++kk) {
            const half8 bf = *reinterpret_cast<const half8*>(
                hc + ((kk * 4 + lg) * 8 + row8) * 16);
            const char* wc = wlds + ((kk - 12) * 4 + lg) * 8192;
            #pragma unroll
            for (int jt = 0; jt < 8; ++jt) {
                const half8 a = *reinterpret_cast<const half8*>(
                    wc + (w * 128 + jt * 16 + l15) * 16);
                acc[jt] = __builtin_amdgcn_mfma_f32_16x16x32_f16(a, bf, acc[jt], 0, 0, 0);
            }
        }

        // ---- issue xp loads for t+1 BEFORE the out stores (oldest-first vmcnt:
        //      consuming these later needs vmcnt(8), not a store drain) ----
        u64 xn[8];
        if (t + 1 < S_SZ) {
            const _Float16* xpb = xp16 + ((size_t)(t + 1) * 64 + r * 8 + row8) * 512 + w * 128 + lg * 4;
            #pragma unroll
            for (int jt = 0; jt < 8; ++jt)
                xn[jt] = *reinterpret_cast<const u64*>(xpb + jt * 16);
        }

        // ---- tanh + h-write (layout [kk][lg][row]) + out stores ----
        const int orow_idx = r * 8 + l15;
        float* orow = out + ((size_t)t * 64 + orow_idx) * 512 + w * 128 + lg * 4;
        #pragma unroll
        for (int jt = 0; jt < 8; ++jt) {
            union { _Float16 h[4]; u64 u; } xv, hp;
            xv.u = xq[jt];
            f32x4 f;
            #pragma unroll
            for (int q = 0; q < 4; ++q) {
                f[q] = fast_tanh(acc[jt][q] + (float)xv.h[q]);
                hp.h[q] = (_Float16)f[q];
            }
            if (primary) {
                const int e = ((w * 4 + (jt >> 1)) * 4 + 2 * (jt & 1) + (lg >> 1)) * 8 + l15;
                *reinterpret_cast<u64*>(hn + e * 16 + (lg & 1) * 8) = hp.u;
                *reinterpret_cast<f32x4*>(orow + jt * 16) = f;
                if (t == S_SZ - 1) {
                    const int j0 = w * 128 + jt * 16 + lg * 4;
                    #pragma unroll
                    for (int q = 0; q < 4; ++q)
                        out[OUT1_OFF + (size_t)(j0 + q) * 64 + orow_idx] = f[q];
                }
            }
        }

        if (t + 1 < S_SZ) {
            #pragma unroll
            for (int jt = 0; jt < 8; ++jt) xq[jt] = xn[jt];
        }

        // ---- LDS-only barrier: drain ds ops, DO NOT drain vmcnt ----
        asm volatile("s_waitcnt lgkmcnt(0)" ::: "memory");
        __builtin_amdgcn_sched_barrier(0);
        __builtin_amdgcn_s_barrier();
        __builtin_amdgcn_sched_barrier(0);
    }
}

extern "C" void kernel_launch(void* const* d_in, const int* in_sizes, int n_in,
                              void* d_out, int out_size, void* d_ws, size_t ws_size,
                              hipStream_t stream)
{
    const float* inputs = (const float*)d_in[0];
    const float* state  = (const float*)d_in[1];
    const float* w_ih   = (const float*)d_in[2];
    const float* b_ih   = (const float*)d_in[3];
    const float* w_hh   = (const float*)d_in[4];
    const float* b_hh   = (const float*)d_in[5];
    float* out = (float*)d_out;
    char* ws = (char*)d_ws;

    _Float16* xp16  = (_Float16*)(ws + XP_OFF);
    _Float16* whh16 = (_Float16*)(ws + WHH_OFF);
    _Float16* wih16 = (_Float16*)(ws + WIH_OFF);
    float*    bias  = (float*)(ws + BIAS_OFF);

    hipFuncSetAttribute((const void*)rnn_step_kernel,
                        hipFuncAttributeMaxDynamicSharedMemorySize, SMEM_SZ);

    prep_kernel<<<1024, 256, 0, stream>>>(w_ih, w_hh, b_ih, b_hh, wih16, whh16, bias);
    xproj_kernel<<<S_SZ, 512, 0, stream>>>(inputs, wih16, bias, xp16);
    rnn_step_kernel<<<8, 256, SMEM_SZ, stream>>>(whh16, xp16, state, out);
}

// Round 12
// 6852.309 us; speedup vs baseline: 1.4962x; 1.4962x over previous
//
#include <hip/hip_runtime.h>

// Tanh RNN: B=64, S=2048, I=H=512, fp32 in/out.
//
// Round 12 = round 11 with the epilogue-coverage bug FIXED:
//   lanes l15<8 handle jt 0..3, lanes l15>=8 handle jt 4..7 (round 11 wrote
//   only jt {0,1}/{2,3} -> j 64..127 of every wave never updated).
// Deltas vs verified round 8 (6823 us rnn):
//  (1) LDS-only barrier: s_waitcnt lgkmcnt(0) + raw s_barrier (no vmcnt drain;
//      out-store acks retire during next step's MFMA phase).
//  (2) Split epilogue across duplicate lanes: halves tanh VALU per lane and
//      balances h/out stores across all 64 lanes. Register indices stay
//      compile-time (hi ? acc[i+4] : acc[i]); only addresses are lane-varying.
//
// Structure (verified round 8): 8 WGs, zero inter-WG comm; WG r owns batch
// rows r*8..+8, full j range. Weights: kk0..7 in AGPR (64 frags, "+a" pin),
// kk8..11 in VGPR (32 frags, "+v" pin), kk12..15 in LDS. h double-buffer in
// LDS as [kk][lg][row] 16B entries. 4 waves, wave w owns j in [w*128,+128),
// one barrier per step.

typedef _Float16 half8 __attribute__((ext_vector_type(8)));
typedef _Float16 half4 __attribute__((ext_vector_type(4)));
typedef float f32x4 __attribute__((ext_vector_type(4)));
typedef unsigned long long u64;

#define S_SZ 2048
#define OUT1_OFF 67108864ull   // S*B*H floats

// workspace offsets (bytes)
#define XP_OFF    0ull              // 2048*64*512*2 = 134217728
#define WHH_OFF   134217728ull      // 524288
#define WIH_OFF   134742016ull      // 524288
#define BIAS_OFF  135266304ull      // 2048

#define WLDS_SZ   131072            // 16 chunks * 8192 B (kk 12..15 x lg 0..3)
#define HB_SZ     8192              // one h buffer: 16kk*4lg*8row*16B
#define SMEM_SZ   147456            // WLDS + 2*HB

__device__ __forceinline__ float fast_tanh(float x) {
    float a = exp2f(x * 2.8853900817779268f);
    return (a - 1.0f) * __builtin_amdgcn_rcpf(a + 1.0f);
}

__global__ void prep_kernel(const float* __restrict__ wih, const float* __restrict__ whh,
                            const float* __restrict__ bih, const float* __restrict__ bhh,
                            _Float16* __restrict__ wih16, _Float16* __restrict__ whh16,
                            float* __restrict__ bias)
{
    const int i = blockIdx.x * 256 + threadIdx.x;   // 1024 blocks -> 262144
    wih16[i] = (_Float16)wih[i];
    whh16[i] = (_Float16)whh[i];
    if (i < 512) bias[i] = bih[i] + bhh[i];
}

// ---------------- input projection GEMM (verified rounds 3-8) ----------------
__global__ __launch_bounds__(512, 1) void xproj_kernel(
    const float* __restrict__ inputs, const _Float16* __restrict__ wih16,
    const float* __restrict__ bias, _Float16* __restrict__ xp16)
{
    __shared__ _Float16 Alds[64 * 512];
    const int s = blockIdx.x;

    for (int idx = threadIdx.x; idx < 64 * 128; idx += 512) {
        const int row = idx >> 7, chunk = idx & 127;
        const float4 v = *reinterpret_cast<const float4*>(
            inputs + ((size_t)row * S_SZ + s) * 512 + chunk * 4);
        half4 hv;
        hv[0] = (_Float16)v.x; hv[1] = (_Float16)v.y;
        hv[2] = (_Float16)v.z; hv[3] = (_Float16)v.w;
        const int bc = (chunk * 8) ^ ((row & 7) << 4);
        *reinterpret_cast<half4*>(reinterpret_cast<char*>(Alds) + row * 1024 + bc) = hv;
    }
    __syncthreads();

    const int lane = threadIdx.x & 63, w = threadIdx.x >> 6;
    const int l15 = lane & 15, lg = lane >> 4;

    f32x4 acc[4][4];
    #pragma unroll
    for (int m = 0; m < 4; ++m)
        #pragma unroll
        for (int n = 0; n < 4; ++n)
            acc[m][n] = 0.0f;

    for (int kk = 0; kk < 16; ++kk) {
        half8 af[4], bf[4];
        #pragma unroll
        for (int m = 0; m < 4; ++m) {
            const int row = m * 16 + l15;
            const int bc = (kk * 64 + lg * 16) ^ ((row & 7) << 4);
            af[m] = *reinterpret_cast<const half8*>(
                reinterpret_cast<const char*>(Alds) + row * 1024 + bc);
        }
        #pragma unroll
        for (int n = 0; n < 4; ++n) {
            const int col = w * 64 + n * 16 + l15;
            bf[n] = *reinterpret_cast<const half8*>(wih16 + (size_t)col * 512 + kk * 32 + lg * 8);
        }
        #pragma unroll
        for (int m = 0; m < 4; ++m)
            #pragma unroll
            for (int n = 0; n < 4; ++n)
                acc[m][n] = __builtin_amdgcn_mfma_f32_16x16x32_f16(bf[n], af[m], acc[m][n], 0, 0, 0);
    }

    #pragma unroll
    for (int m = 0; m < 4; ++m) {
        const int brow = m * 16 + l15;
        #pragma unroll
        for (int n = 0; n < 4; ++n) {
            const int j0 = w * 64 + n * 16 + lg * 4;
            const float4 bv = *reinterpret_cast<const float4*>(bias + j0);
            half4 hv;
            hv[0] = (_Float16)(acc[m][n][0] + bv.x);
            hv[1] = (_Float16)(acc[m][n][1] + bv.y);
            hv[2] = (_Float16)(acc[m][n][2] + bv.z);
            hv[3] = (_Float16)(acc[m][n][3] + bv.w);
            *reinterpret_cast<half4*>(xp16 + ((size_t)s * 64 + brow) * 512 + j0) = hv;
        }
    }
}

// ---------------- recurrence ----------------
__global__ __launch_bounds__(256, 1) void rnn_step_kernel(
    const _Float16* __restrict__ whh16, const _Float16* __restrict__ xp16,
    const float* __restrict__ state, float* __restrict__ out)
{
    extern __shared__ __align__(16) char smem[];
    char* wlds = smem;                 // 16 chunks * 8192
    char* hb   = smem + WLDS_SZ;       // 2 * 8192

    const int r = blockIdx.x;          // 0..7: batch rows r*8..+8
    const int tid = threadIdx.x;
    const int lane = tid & 63, w = tid >> 6;   // 4 waves; wave w: j in [w*128, +128)
    const int l15 = lane & 15, lg = lane >> 4;
    const int row8 = l15 & 7;
    const bool hi = (l15 >= 8);        // epilogue half: jt 4..7

    // --- stage W-LDS (kk 12..15), linear: chunk c=(kk-12)*4+lgc, entry jj ---
    for (int idx = tid; idx < 16 * 512; idx += 256) {
        const int c = idx >> 9, jj = idx & 511;
        const int kk = 12 + (c >> 2), lgc = c & 3;
        *reinterpret_cast<half8*>(wlds + c * 8192 + jj * 16) =
            *reinterpret_cast<const half8*>(whh16 + (size_t)jj * 512 + kk * 32 + lgc * 8);
    }
    // --- stage h0 as [kk][lg][row] entries: h[row][kk*32+lg*8 .. +8] ---
    for (int idx = tid; idx < 512; idx += 256) {
        const int row = idx & 7, lgc = (idx >> 3) & 3, kk = idx >> 5;
        const float* sp = state + (size_t)(r * 8 + row) * 512 + kk * 32 + lgc * 8;
        const float4 v0 = *reinterpret_cast<const float4*>(sp);
        const float4 v1 = *reinterpret_cast<const float4*>(sp + 4);
        half8 hv;
        hv[0] = (_Float16)v0.x; hv[1] = (_Float16)v0.y;
        hv[2] = (_Float16)v0.z; hv[3] = (_Float16)v0.w;
        hv[4] = (_Float16)v1.x; hv[5] = (_Float16)v1.y;
        hv[6] = (_Float16)v1.z; hv[7] = (_Float16)v1.w;
        *reinterpret_cast<half8*>(hb + ((kk * 4 + lgc) * 8 + row) * 16) = hv;
    }

    // --- register weights: wa (kk0..7 -> AGPR) + wv (kk8..11 -> VGPR) ---
    half8 wa[64], wv[32];
    {
        const _Float16* wp = whh16 + (size_t)(w * 128 + l15) * 512 + lg * 8;
        #pragma unroll
        for (int jt = 0; jt < 8; ++jt) {
            #pragma unroll
            for (int kk = 0; kk < 8; ++kk)
                wa[jt * 8 + kk] = *reinterpret_cast<const half8*>(wp + jt * 16 * 512 + kk * 32);
            #pragma unroll
            for (int kk = 8; kk < 12; ++kk)
                wv[jt * 4 + kk - 8] = *reinterpret_cast<const half8*>(wp + jt * 16 * 512 + kk * 32);
        }
    }
    // pin: opaque def blocks remat; "a"/"v" fixes the register class.
    #pragma unroll
    for (int i = 0; i < 64; ++i) asm volatile("" : "+a"(wa[i]));
    #pragma unroll
    for (int i = 0; i < 32; ++i) asm volatile("" : "+v"(wv[i]));

    // --- xp prefetch for t=0 (this lane's 4 jt only) ---
    u64 xq[4];
    {
        const _Float16* xpb = xp16 + (size_t)(r * 8 + row8) * 512
                              + w * 128 + (hi ? 64 : 0) + lg * 4;
        #pragma unroll
        for (int i = 0; i < 4; ++i)
            xq[i] = *reinterpret_cast<const u64*>(xpb + i * 16);
    }

    __syncthreads();   // staging barrier (full drain fine here, once)

    #pragma unroll 1
    for (int t = 0; t < S_SZ; ++t) {
        const char* hc = hb + (t & 1) * HB_SZ;
        char* hn = hb + ((t + 1) & 1) * HB_SZ;

        f32x4 acc[8];
        #pragma unroll
        for (int jt = 0; jt < 8; ++jt) acc[jt] = 0.0f;

        // kk 0..7: AGPR-resident weights
        #pragma unroll
        for (int kk = 0; kk < 8; ++kk) {
            const half8 bf = *reinterpret_cast<const half8*>(
                hc + ((kk * 4 + lg) * 8 + row8) * 16);
            #pragma unroll
            for (int jt = 0; jt < 8; ++jt)
                acc[jt] = __builtin_amdgcn_mfma_f32_16x16x32_f16(
                    wa[jt * 8 + kk], bf, acc[jt], 0, 0, 0);
        }
        // kk 8..11: VGPR-resident weights
        #pragma unroll
        for (int kk = 8; kk < 12; ++kk) {
            const half8 bf = *reinterpret_cast<const half8*>(
                hc + ((kk * 4 + lg) * 8 + row8) * 16);
            #pragma unroll
            for (int jt = 0; jt < 8; ++jt)
                acc[jt] = __builtin_amdgcn_mfma_f32_16x16x32_f16(
                    wv[jt * 4 + kk - 8], bf, acc[jt], 0, 0, 0);
        }
        // kk 12..15: weights from LDS
        #pragma unroll
        for (int kk = 12; kk < 16; ++kk) {
            const half8 bf = *reinterpret_cast<const half8*>(
                hc + ((kk * 4 + lg) * 8 + row8) * 16);
            const char* wc = wlds + ((kk - 12) * 4 + lg) * 8192;
            #pragma unroll
            for (int jt = 0; jt < 8; ++jt) {
                const half8 a = *reinterpret_cast<const half8*>(
                    wc + (w * 128 + jt * 16 + l15) * 16);
                acc[jt] = __builtin_amdgcn_mfma_f32_16x16x32_f16(a, bf, acc[jt], 0, 0, 0);
            }
        }

        // ---- split epilogue: lo lanes jt 0..3, hi lanes jt 4..7 ----
        const int rowi = r * 8 + row8;
        #pragma unroll
        for (int i = 0; i < 4; ++i) {
            const f32x4 a = hi ? acc[i + 4] : acc[i];   // static idx both arms
            union { _Float16 h[4]; u64 u; } xv, hp;
            xv.u = xq[i];
            f32x4 f;
            #pragma unroll
            for (int q = 0; q < 4; ++q) {
                f[q] = fast_tanh(a[q] + (float)xv.h[q]);
                hp.h[q] = (_Float16)f[q];
            }
            const int j0 = w * 128 + (hi ? 64 : 0) + i * 16 + lg * 4;  // lane-varying addr
            // h-write: entry e = (kk*4+lgc)*8+row, kk=j0>>5, lgc=(j0>>3)&3
            const int e = (((j0 >> 5) * 4 + ((j0 >> 3) & 3)) * 8 + row8);
            *reinterpret_cast<u64*>(hn + e * 16 + (lg & 1) * 8) = hp.u;
            // out store
            *reinterpret_cast<f32x4*>(out + ((size_t)t * 64 + rowi) * 512 + j0) = f;
            if (t == S_SZ - 1) {
                #pragma unroll
                for (int q = 0; q < 4; ++q)
                    out[OUT1_OFF + (size_t)(j0 + q) * 64 + rowi] = f[q];
            }
        }

        // ---- xp reload for t+1 (after stores; its vmcnt wait lands next iter,
        //      ~1800cy later, by which time the out-store acks have drained) ----
        if (t + 1 < S_SZ) {
            const _Float16* xpb = xp16 + ((size_t)(t + 1) * 64 + rowi) * 512
                                  + w * 128 + (hi ? 64 : 0) + lg * 4;
            #pragma unroll
            for (int i = 0; i < 4; ++i)
                xq[i] = *reinterpret_cast<const u64*>(xpb + i * 16);
        }

        // ---- LDS-only barrier: drain ds ops only; no vmcnt drain ----
        asm volatile("s_waitcnt lgkmcnt(0)" ::: "memory");
        __builtin_amdgcn_s_barrier();
    }
}

extern "C" void kernel_launch(void* const* d_in, const int* in_sizes, int n_in,
                              void* d_out, int out_size, void* d_ws, size_t ws_size,
                              hipStream_t stream)
{
    const float* inputs = (const float*)d_in[0];
    const float* state  = (const float*)d_in[1];
    const float* w_ih   = (const float*)d_in[2];
    const float* b_ih   = (const float*)d_in[3];
    const float* w_hh   = (const float*)d_in[4];
    const float* b_hh   = (const float*)d_in[5];
    float* out = (float*)d_out;
    char* ws = (char*)d_ws;

    _Float16* xp16  = (_Float16*)(ws + XP_OFF);
    _Float16* whh16 = (_Float16*)(ws + WHH_OFF);
    _Float16* wih16 = (_Float16*)(ws + WIH_OFF);
    float*    bias  = (float*)(ws + BIAS_OFF);

    hipFuncSetAttribute((const void*)rnn_step_kernel,
                        hipFuncAttributeMaxDynamicSharedMemorySize, SMEM_SZ);

    prep_kernel<<<1024, 256, 0, stream>>>(w_ih, w_hh, b_ih, b_hh, wih16, whh16, bias);
    xproj_kernel<<<S_SZ, 512, 0, stream>>>(inputs, wih16, bias, xp16);
    rnn_step_kernel<<<8, 256, SMEM_SZ, stream>>>(whh16, xp16, state, out);
}